// Round 3
// baseline (384.202 us; speedup 1.0000x reference)
//
#include <hip/hip_runtime.h>
#include <hip/hip_fp16.h>

// Problem constants (fixed by setup_inputs): B=1, KVH=8, D=128, S=8192
#define HH 8
#define DD 128
#define SS 8192

#define KEYS_BLOCKS 256   // 8 heads * 32 s-tiles of 256 s
#define VALS_BLOCKS 4096  // 65536 rows / 16 rows per block
#define ATTN_BLOCKS 4096  // 16777216 float4 / (512 threads * 8 float4)

// native 4-float vector for __builtin_nontemporal_store (HIP_vector_type is rejected)
typedef float nfloat4 __attribute__((ext_vector_type(4)));

// One fused kernel: block-range switch. keys/vals (readers) get low block IDs so
// their loads start first; attn (pure writer) floods the remaining capacity.
// This mixes read+write streams at the HBM controller and gives a single
// observable dispatch time.
__global__ __launch_bounds__(512) void fused_kernel(
    const float* __restrict__ keys, const float* __restrict__ vals,
    const int* __restrict__ maskp,
    float* __restrict__ attn, float* __restrict__ kp, float* __restrict__ ks,
    float* __restrict__ kb, float* __restrict__ vp, float* __restrict__ vs,
    float* __restrict__ vbias)
{
    const int bid = blockIdx.x;
    const int tid = threadIdx.x;

    __shared__ float4 smin[8][64], smax[8][64];
    __shared__ float4 sbias[64], sinv[64];

    if (bid < KEYS_BLOCKS) {
        // ---- keys: (H, D, S), quantize over D (stride 32 KB). Tile = 256 s x 128 d.
        // Wave = 64 lanes x float4 -> 1 KB contiguous per load/store instruction.
        const int h   = bid >> 5;
        const int s04 = (bid & 31) << 6;  // float4 offset of s-tile (64 float4 = 256 s)
        const int l   = tid & 63;
        const int w   = tid >> 6;         // 0..7, owns d rows w*16 .. w*16+15
        const float4* k4 = (const float4*)keys;

        float4 val[16];
        float4 mn4 = make_float4(3e38f, 3e38f, 3e38f, 3e38f);
        float4 mx4 = make_float4(-3e38f, -3e38f, -3e38f, -3e38f);
#pragma unroll
        for (int j = 0; j < 16; ++j) {
            float4 v = k4[(size_t)(h * DD + w * 16 + j) * (SS / 4) + s04 + l];
            val[j] = v;
            mn4.x = fminf(mn4.x, v.x); mn4.y = fminf(mn4.y, v.y);
            mn4.z = fminf(mn4.z, v.z); mn4.w = fminf(mn4.w, v.w);
            mx4.x = fmaxf(mx4.x, v.x); mx4.y = fmaxf(mx4.y, v.y);
            mx4.z = fmaxf(mx4.z, v.z); mx4.w = fmaxf(mx4.w, v.w);
        }
        smin[w][l] = mn4;
        smax[w][l] = mx4;
        __syncthreads();
        if (w == 0) {
            float4 m = smin[0][l], M = smax[0][l];
#pragma unroll
            for (int i = 1; i < 8; ++i) {
                float4 a = smin[i][l], b = smax[i][l];
                m.x = fminf(m.x, a.x); m.y = fminf(m.y, a.y);
                m.z = fminf(m.z, a.z); m.w = fminf(m.w, a.w);
                M.x = fmaxf(M.x, b.x); M.y = fmaxf(M.y, b.y);
                M.z = fmaxf(M.z, b.z); M.w = fmaxf(M.w, b.w);
            }
            float4 sc;  // fp32 scale, matches (max-min)*(1/QMAX) before astype
            sc.x = (M.x - m.x) * (1.0f / 255.0f); sc.y = (M.y - m.y) * (1.0f / 255.0f);
            sc.z = (M.z - m.z) * (1.0f / 255.0f); sc.w = (M.w - m.w) * (1.0f / 255.0f);
            float4 kso, kbo;  // astype(f16) round-trip, RNE
            kso.x = __half2float(__float2half(sc.x)); kso.y = __half2float(__float2half(sc.y));
            kso.z = __half2float(__float2half(sc.z)); kso.w = __half2float(__float2half(sc.w));
            kbo.x = __half2float(__float2half(m.x)); kbo.y = __half2float(__float2half(m.y));
            kbo.z = __half2float(__float2half(m.z)); kbo.w = __half2float(__float2half(m.w));
            ((float4*)ks)[h * (SS / 4) + s04 + l] = kso;
            ((float4*)kb)[h * (SS / 4) + s04 + l] = kbo;
            float4 inv;  // hoist reciprocal: 1 div/column instead of 1 div/element
            inv.x = 1.0f / sc.x; inv.y = 1.0f / sc.y;
            inv.z = 1.0f / sc.z; inv.w = 1.0f / sc.w;
            sbias[l] = m;
            sinv[l]  = inv;
        }
        __syncthreads();
        const float4 b4 = sbias[l];
        const float4 i4 = sinv[l];
        float4* o4 = (float4*)kp;
#pragma unroll
        for (int j = 0; j < 16; ++j) {
            float4 o;
            o.x = rintf((val[j].x - b4.x) * i4.x);
            o.y = rintf((val[j].y - b4.y) * i4.y);
            o.z = rintf((val[j].z - b4.z) * i4.z);
            o.w = rintf((val[j].w - b4.w) * i4.w);
            o4[(size_t)(h * DD + w * 16 + j) * (SS / 4) + s04 + l] = o;
        }
    } else if (bid < KEYS_BLOCKS + VALS_BLOCKS) {
        // ---- values: (H, S, D), quantize over contiguous D=128. 32 lanes/row.
        const int vbd = bid - KEYS_BLOCKS;
        const int d4  = tid & 31;
        const int rr  = tid >> 5;           // 0..15 rows per block
        const int R   = vbd * 16 + rr;      // flat row = h*8192 + s

        const float4 v = ((const float4*)vals)[R * 32 + d4];
        float mn = fminf(fminf(v.x, v.y), fminf(v.z, v.w));
        float mx = fmaxf(fmaxf(v.x, v.y), fmaxf(v.z, v.w));
#pragma unroll
        for (int off = 16; off >= 1; off >>= 1) {  // stays within 32-lane group
            mn = fminf(mn, __shfl_xor(mn, off));
            mx = fmaxf(mx, __shfl_xor(mx, off));
        }
        const float scale = (mx - mn) * (1.0f / 255.0f);
        const float inv = 1.0f / scale;
        if (d4 == 0) {
            // v_scale swapaxes(-1,-2) is a flat no-op: both flat [h][s] = [R]
            vs[R]    = __half2float(__float2half(scale));
            vbias[R] = __half2float(__float2half(mn));
        }
        float4 o;
        o.x = rintf((v.x - mn) * inv);
        o.y = rintf((v.y - mn) * inv);
        o.z = rintf((v.z - mn) * inv);
        o.w = rintf((v.w - mn) * inv);
        ((float4*)vp)[R * 32 + d4] = o;
    } else {
        // ---- attn mask fill: out[r][c] = (c>r ? -128 : 0) * mask. 64 KB/block.
        const int ab = bid - (KEYS_BLOCKS + VALS_BLOCKS);
        const float hi = (float)(-128 * (*maskp));
        const int base = ab * 4096 + tid;   // float4 index
        nfloat4* o4 = (nfloat4*)attn;
#pragma unroll
        for (int k2 = 0; k2 < 8; ++k2) {
            int idx = base + k2 * 512;
            int r = idx >> 11;
            int c = (idx & 2047) << 2;
            nfloat4 v;
            v.x = (c + 0 > r) ? hi : 0.0f;
            v.y = (c + 1 > r) ? hi : 0.0f;
            v.z = (c + 2 > r) ? hi : 0.0f;
            v.w = (c + 3 > r) ? hi : 0.0f;
            __builtin_nontemporal_store(v, &o4[idx]);  // 268 MB single-use stream
        }
    }
}

extern "C" void kernel_launch(void* const* d_in, const int* in_sizes, int n_in,
                              void* d_out, int out_size, void* d_ws, size_t ws_size,
                              hipStream_t stream) {
    const float* keys  = (const float*)d_in[0];
    const float* vals  = (const float*)d_in[1];
    const int*   maskp = (const int*)d_in[2];

    float* out  = (float*)d_out;
    float* attn = out;              // 8192*8192    = 67108864
    float* kp   = attn + 67108864;  // 8*128*8192   =  8388608
    float* ks   = kp   + 8388608;   // 8*8192       =    65536
    float* kb   = ks   + 65536;
    float* vp   = kb   + 65536;     //                 8388608
    float* vs   = vp   + 8388608;
    float* vbv  = vs   + 65536;

    const int grid = KEYS_BLOCKS + VALS_BLOCKS + ATTN_BLOCKS;
    fused_kernel<<<dim3(grid), dim3(512), 0, stream>>>(
        keys, vals, maskp, attn, kp, ks, kb, vp, vs, vbv);
}